// Round 2
// baseline (273.152 us; speedup 1.0000x reference)
//
#include <hip/hip_runtime.h>

#define NDATA 262144
#define SD 8
#define HL 16
#define NN 16
#define ROWLEN (SD * (1 + NN))   // 136 floats per input row
#define RPG 4                    // rows per 16-lane group

// 16-lane allreduce via DPP row_ror steps (row = 16 lanes on CDNA).
// Each step: v_mov_dpp + v_add_f32 — no DS ops, no address math.
// ror:8,4,2,1 combine disjoint index halves -> full sum in all 16 lanes.
__device__ __forceinline__ float group_allreduce(float v) {
    int t;
    t = __builtin_amdgcn_update_dpp(0, __float_as_int(v), 0x128, 0xF, 0xF, true); // row_ror:8
    v += __int_as_float(t);
    t = __builtin_amdgcn_update_dpp(0, __float_as_int(v), 0x124, 0xF, 0xF, true); // row_ror:4
    v += __int_as_float(t);
    t = __builtin_amdgcn_update_dpp(0, __float_as_int(v), 0x122, 0xF, 0xF, true); // row_ror:2
    v += __int_as_float(t);
    t = __builtin_amdgcn_update_dpp(0, __float_as_int(v), 0x121, 0xF, 0xF, true); // row_ror:1
    v += __int_as_float(t);
    return v;
}

// One 16-lane group handles RPG consecutive rows; lane j = neighbor j.
// Weight-outer / row-inner loops: every weight fetch feeds RPG FMAs.
__global__ __launch_bounds__(256) void deepset_kernel(
    const float* __restrict__ x,
    const float* __restrict__ phi_w1, const float* __restrict__ phi_b1,
    const float* __restrict__ phi_w2, const float* __restrict__ phi_b2,
    const float* __restrict__ rho_w1, const float* __restrict__ rho_b1,
    const float* __restrict__ rho_w2, const float* __restrict__ rho_b2,
    float* __restrict__ out)
{
    const int tid = blockIdx.x * blockDim.x + threadIdx.x;
    const int g   = tid >> 4;        // group id
    const int j   = tid & 15;        // lane-in-group = neighbor index
    const long row0 = (long)g * RPG;
    const float* __restrict__ xr0 = x + row0 * ROWLEN;

    // ---- neighbor features for RPG rows (coalesced: 16 lanes x 4B per (r,d))
    float nb[RPG][SD];
#pragma unroll
    for (int r = 0; r < RPG; ++r)
#pragma unroll
        for (int d = 0; d < SD; ++d)
            nb[r][d] = xr0[r * ROWLEN + SD + d * NN + j];

    // ---- phi: interleaved layer1/layer2, streaming over the 32 hidden units.
    // acc[r][k] accumulates phi2 pre-activation for row r's neighbor j.
    float acc[RPG][HL];
#pragma unroll
    for (int r = 0; r < RPG; ++r)
#pragma unroll
        for (int k = 0; k < HL; ++k)
            acc[r][k] = 0.0f;

#pragma unroll
    for (int o = 0; o < 32; ++o) {
        const float b1 = phi_b1[o];
        float t[RPG];
#pragma unroll
        for (int r = 0; r < RPG; ++r) t[r] = b1;
#pragma unroll
        for (int d = 0; d < SD; ++d) {
            const float w = phi_w1[o * SD + d];
#pragma unroll
            for (int r = 0; r < RPG; ++r)
                t[r] = fmaf(w, nb[r][d], t[r]);
        }
#pragma unroll
        for (int r = 0; r < RPG; ++r) t[r] = fmaxf(t[r], 0.0f);
#pragma unroll
        for (int k = 0; k < HL; ++k) {
            const float w = phi_w2[k * 32 + o];
#pragma unroll
            for (int r = 0; r < RPG; ++r)
                acc[r][k] = fmaf(w, t[r], acc[r][k]);
        }
    }

    // ---- per-neighbor bias + relu, then sum over the 16 neighbors (DPP).
#pragma unroll
    for (int k = 0; k < HL; ++k) {
        const float b2 = phi_b2[k];
#pragma unroll
        for (int r = 0; r < RPG; ++r)
            acc[r][k] = group_allreduce(fmaxf(acc[r][k] + b2, 0.0f));
    }
    // acc[r][k] == summ[row0+r][k] in every lane of the group.

    // ---- state features (nb regs are dead now; broadcast loads, L1 hits)
    float sv[RPG][SD];
#pragma unroll
    for (int r = 0; r < RPG; ++r)
#pragma unroll
        for (int d = 0; d < SD; ++d)
            sv[r][d] = xr0[r * ROWLEN + d];

    // ---- rho layer 1: lane j owns outputs o0=2j, 2j+1 (rows contiguous, coalesced)
    const int o0 = 2 * j;
    const float* __restrict__ w0 = rho_w1 + (o0 + 0) * (SD + HL);
    const float* __restrict__ w1 = rho_w1 + (o0 + 1) * (SD + HL);
    float y0[RPG], y1[RPG];
    {
        const float bb0 = rho_b1[o0 + 0];
        const float bb1 = rho_b1[o0 + 1];
#pragma unroll
        for (int r = 0; r < RPG; ++r) { y0[r] = bb0; y1[r] = bb1; }
    }
#pragma unroll
    for (int d = 0; d < SD; ++d) {
        const float a0 = w0[d];
        const float a1 = w1[d];
#pragma unroll
        for (int r = 0; r < RPG; ++r) {
            y0[r] = fmaf(a0, sv[r][d], y0[r]);
            y1[r] = fmaf(a1, sv[r][d], y1[r]);
        }
    }
#pragma unroll
    for (int k = 0; k < HL; ++k) {
        const float a0 = w0[SD + k];
        const float a1 = w1[SD + k];
#pragma unroll
        for (int r = 0; r < RPG; ++r) {
            y0[r] = fmaf(a0, acc[r][k], y0[r]);
            y1[r] = fmaf(a1, acc[r][k], y1[r]);
        }
    }
#pragma unroll
    for (int r = 0; r < RPG; ++r) {
        y0[r] = fmaxf(y0[r], 0.0f);
        y1[r] = fmaxf(y1[r], 0.0f);
    }

    // ---- rho layer 2: per-lane partials (weights amortized over RPG rows)
    const float z00 = rho_w2[0 * 32 + o0], z01 = rho_w2[0 * 32 + o0 + 1];
    const float z10 = rho_w2[1 * 32 + o0], z11 = rho_w2[1 * 32 + o0 + 1];
    const float rb0 = rho_b2[0], rb1 = rho_b2[1];

#pragma unroll
    for (int r = 0; r < RPG; ++r) {
        float p0 = group_allreduce(fmaf(z00, y0[r], z01 * y1[r]));
        float p1 = group_allreduce(fmaf(z10, y0[r], z11 * y1[r]));
        if (j == 0) {
            float2 res;
            res.x = fmaxf(p0 + rb0, 0.0f);
            res.y = fmaxf(p1 + rb1, 0.0f);
            reinterpret_cast<float2*>(out)[row0 + r] = res;
        }
    }
}

extern "C" void kernel_launch(void* const* d_in, const int* in_sizes, int n_in,
                              void* d_out, int out_size, void* d_ws, size_t ws_size,
                              hipStream_t stream) {
    const float* x      = (const float*)d_in[0];
    const float* phi_w1 = (const float*)d_in[1];
    const float* phi_b1 = (const float*)d_in[2];
    const float* phi_w2 = (const float*)d_in[3];
    const float* phi_b2 = (const float*)d_in[4];
    const float* rho_w1 = (const float*)d_in[5];
    const float* rho_b1 = (const float*)d_in[6];
    const float* rho_w2 = (const float*)d_in[7];
    const float* rho_b2 = (const float*)d_in[8];
    float* out = (float*)d_out;

    const int threads = 256;
    const long total  = (long)NDATA / RPG * 16;   // one thread per (group-lane)
    const int blocks  = (int)(total / threads);   // 4096, exact

    deepset_kernel<<<blocks, threads, 0, stream>>>(
        x, phi_w1, phi_b1, phi_w2, phi_b2,
        rho_w1, rho_b1, rho_w2, rho_b2, out);
}

// Round 7
// 252.920 us; speedup vs baseline: 1.0800x; 1.0800x over previous
//
#include <hip/hip_runtime.h>

#define NDATA 262144
#define SD 8
#define HL 16
#define NN 16
#define ROWLEN 136           // 8 + 8*16 floats per input row
#define NB 4                 // 8-row batches per wave

typedef __attribute__((ext_vector_type(8)))  short bf16x8;
typedef __attribute__((ext_vector_type(16))) float f32x16;

// f32 -> bf16 (RNE), setup-path helper
__device__ __forceinline__ unsigned short f2bf(float f) {
    unsigned u = __float_as_uint(f);
    return (unsigned short)((u + 0x7FFFu + ((u >> 16) & 1u)) >> 16);
}
__device__ __forceinline__ unsigned pk2(float lo, float hi) {
    return (unsigned)f2bf(lo) | ((unsigned)f2bf(hi) << 16);
}
// hot-path packed convert (1 instr): D[15:0]=bf16(a), D[31:16]=bf16(b)
__device__ __forceinline__ unsigned cvtpk(float a, float b) {
    unsigned r;
    asm("v_cvt_pk_bf16_f32 %0, %1, %2" : "=v"(r) : "v"(a), "v"(b));
    return r;
}
// V_PERMLANE32_SWAP_B32: swaps a's high-32-lane values with b's low-32-lane
// values. Post: a = {a.lo-lanes, b.lo-lanes}, b = {a.hi-lanes, b.hi-lanes}.
__device__ __forceinline__ void plswap(unsigned &a, unsigned &b) {
    asm volatile("v_permlane32_swap_b32 %0, %1" : "+v"(a), "+v"(b));
}
union FragU { unsigned u[4]; bf16x8 v; };

// 16-lane allreduce via DPP row_ror
__device__ __forceinline__ float group_allreduce(float v) {
    int t;
    t = __builtin_amdgcn_update_dpp(0, __float_as_int(v), 0x128, 0xF, 0xF, true);
    v += __int_as_float(t);
    t = __builtin_amdgcn_update_dpp(0, __float_as_int(v), 0x124, 0xF, 0xF, true);
    v += __int_as_float(t);
    t = __builtin_amdgcn_update_dpp(0, __float_as_int(v), 0x122, 0xF, 0xF, true);
    v += __int_as_float(t);
    t = __builtin_amdgcn_update_dpp(0, __float_as_int(v), 0x121, 0xF, 0xF, true);
    v += __int_as_float(t);
    return v;
}

// Layout facts used (32x32x16 bf16 MFMA):
//   A-frag: lane l holds A[m=l&31][k = 8*(l>>5) + i], i=0..7 (contiguous k)
//   B-frag: lane l holds B[k = 8*(l>>5) + i][n=l&31]
//   D-frag: d[reg] = D[row = (reg&3)+8*(reg>>2)+4*(l>>5)][col = l&31]
__global__ __launch_bounds__(256) void deepset_kernel(
    const float* __restrict__ x,
    const float* __restrict__ phi_w1, const float* __restrict__ phi_b1,
    const float* __restrict__ phi_w2, const float* __restrict__ phi_b2,
    const float* __restrict__ rho_w1, const float* __restrict__ rho_b1,
    const float* __restrict__ rho_w2, const float* __restrict__ rho_b2,
    float* __restrict__ out)
{
    __shared__ float lds_summ[4][8][16];   // [wave][local row][k]

    const int lane = threadIdx.x & 63;
    const int w    = threadIdx.x >> 6;
    const int h    = lane >> 5;            // wave half = k-half owner
    const int n31  = lane & 31;            // MFMA 32-col id
    const int c    = n31 & 15;             // neighbor index
    const int p    = n31 >> 4;             // row parity within pass

    // ---- A1 = [W1 | b1] (32 x 9, padded to K=16): h=0 holds k=0..7 (features),
    //      h=1 holds k=8..15 (bias at k=8, zeros beyond).
    FragU a1;
    if (h == 0) {
        const float* wr = phi_w1 + n31 * SD;
        a1.u[0] = pk2(wr[0], wr[1]);
        a1.u[1] = pk2(wr[2], wr[3]);
        a1.u[2] = pk2(wr[4], wr[5]);
        a1.u[3] = pk2(wr[6], wr[7]);
    } else {
        a1.u[0] = pk2(phi_b1[n31], 0.0f);   // bias at k=8
        a1.u[1] = 0u; a1.u[2] = 0u; a1.u[3] = 0u;
    }

    // ---- B2[kt][k=8h+i][n=n31] = W2[n31][16kt+8h+i] (n31<16, else 0)
    FragU b2[2];
#pragma unroll
    for (int kt = 0; kt < 2; ++kt) {
        const float* wr = phi_w2 + (n31 & 15) * 32 + 16 * kt + 8 * h;
#pragma unroll
        for (int q = 0; q < 4; ++q) {
            float e0 = (n31 < HL) ? wr[2 * q]     : 0.0f;
            float e1 = (n31 < HL) ? wr[2 * q + 1] : 0.0f;
            b2[kt].u[q] = pk2(e0, e1);
        }
    }
    const float b2v = phi_b2[n31 & 15];

    const long gw = (long)blockIdx.x * 4 + w;

    for (int b = 0; b < NB; ++b) {
        const long rbase = gw * (8 * NB) + (long)b * 8;

        // ================= phi: 4 passes x (2 rows, 16 neighbors) ==========
#pragma unroll
        for (int t = 0; t < 4; ++t) {
            const long row = rbase + 2 * t + p;
            const float* xb = x + (size_t)row * ROWLEN + SD + c;

            // all 8 features of neighbor c (coalesced 64B x2 rows per d)
            float f0 = xb[0 * NN], f1 = xb[1 * NN], f2 = xb[2 * NN], f3 = xb[3 * NN];
            float f4 = xb[4 * NN], f5 = xb[5 * NN], f6 = xb[6 * NN], f7 = xb[7 * NN];
            FragU b1;
            b1.u[0] = h ? 0x00003F80u : cvtpk(f0, f1);  // h=1: 1.0 at k=8
            b1.u[1] = h ? 0u          : cvtpk(f2, f3);
            b1.u[2] = h ? 0u          : cvtpk(f4, f5);
            b1.u[3] = h ? 0u          : cvtpk(f6, f7);

            f32x16 z = {0,0,0,0,0,0,0,0,0,0,0,0,0,0,0,0};
            f32x16 d1 = __builtin_amdgcn_mfma_f32_32x32x16_bf16(a1.v, b1.v, z, 0, 0, 0);

            // relu(H1); repack D-layout -> A-layout via cvtpk + permlane32_swap
            float r[16];
#pragma unroll
            for (int i = 0; i < 16; ++i) r[i] = fmaxf(d1[i], 0.0f);

            FragU a2[2];
#pragma unroll
            for (int kt = 0; kt < 2; ++kt) {
                unsigned wa0 = cvtpk(r[8 * kt + 0], r[8 * kt + 1]); // rows {0,1}+16kt+4h
                unsigned wa1 = cvtpk(r[8 * kt + 2], r[8 * kt + 3]); // rows {2,3}+16kt+4h
                unsigned wb0 = cvtpk(r[8 * kt + 4], r[8 * kt + 5]); // rows {8,9}+16kt+4h
                unsigned wb1 = cvtpk(r[8 * kt + 6], r[8 * kt + 7]); // rows {10,11}+16kt+4h
                plswap(wa0, wb0);   // -> k = 16kt+8h+{0,1} / {4,5}
                plswap(wa1, wb1);   // -> k = 16kt+8h+{2,3} / {6,7}
                a2[kt].u[0] = wa0; a2[kt].u[1] = wa1;
                a2[kt].u[2] = wb0; a2[kt].u[3] = wb1;
            }

            f32x16 d2 = __builtin_amdgcn_mfma_f32_32x32x16_bf16(a2[0].v, b2[0].v, z, 0, 0, 0);
            d2 = __builtin_amdgcn_mfma_f32_32x32x16_bf16(a2[1].v, b2[1].v, d2, 0, 0, 0);

            // bias+relu; regs 0-7 -> cols m<16 (p=0), regs 8-15 -> m>=16 (p=1)
            float s0 = 0.0f, s1 = 0.0f;
#pragma unroll
            for (int i = 0; i < 8; ++i) {
                s0 += fmaxf(d2[i] + b2v, 0.0f);
                s1 += fmaxf(d2[8 + i] + b2v, 0.0f);
            }
            s0 += __shfl_xor(s0, 32);   // combine the two wave halves
            s1 += __shfl_xor(s1, 32);

            if (n31 < HL)
                lds_summ[w][2 * t + h][n31] = h ? s1 : s0;
        }

        // ================= rho: fp32 VALU, 16-lane group per row ===========
#pragma unroll
        for (int it = 0; it < 2; ++it) {
            const int  lrow = it * 4 + (lane >> 4);
            const long row  = rbase + lrow;
            const int  j16  = lane & 15;
            const float* xr = x + (size_t)row * ROWLEN;
            const float* sm = &lds_summ[w][lrow][0];

            const int o0 = 2 * j16;
            const float* w0  = rho_w1 + (size_t)o0 * (SD + HL);
            const float* w1r = w0 + (SD + HL);
            float y0 = rho_b1[o0], y1 = rho_b1[o0 + 1];
#pragma unroll
            for (int d = 0; d < SD; ++d) {
                const float sv = xr[d];
                y0 = fmaf(w0[d],  sv, y0);
                y1 = fmaf(w1r[d], sv, y1);
            }
#pragma unroll
            for (int k = 0; k < HL; ++k) {
                const float s = sm[k];
                y0 = fmaf(w0[SD + k],  s, y0);
                y1 = fmaf(w1r[SD + k], s, y1);
            }
            y0 = fmaxf(y0, 0.0f);
            y1 = fmaxf(y1, 0.0f);

            float p0 = fmaf(rho_w2[o0],      y0, rho_w2[o0 + 1]      * y1);
            float p1 = fmaf(rho_w2[32 + o0], y0, rho_w2[32 + o0 + 1] * y1);
            p0 = group_allreduce(p0);
            p1 = group_allreduce(p1);

            if (j16 == 0) {
                float2 res;
                res.x = fmaxf(p0 + rho_b2[0], 0.0f);
                res.y = fmaxf(p1 + rho_b2[1], 0.0f);
                reinterpret_cast<float2*>(out)[row] = res;
            }
        }
    }
}

extern "C" void kernel_launch(void* const* d_in, const int* in_sizes, int n_in,
                              void* d_out, int out_size, void* d_ws, size_t ws_size,
                              hipStream_t stream) {
    const float* x      = (const float*)d_in[0];
    const float* phi_w1 = (const float*)d_in[1];
    const float* phi_b1 = (const float*)d_in[2];
    const float* phi_w2 = (const float*)d_in[3];
    const float* phi_b2 = (const float*)d_in[4];
    const float* rho_w1 = (const float*)d_in[5];
    const float* rho_b1 = (const float*)d_in[6];
    const float* rho_w2 = (const float*)d_in[7];
    const float* rho_b2 = (const float*)d_in[8];
    float* out = (float*)d_out;

    // rows per block = 4 waves * 8 rows * NB = 128
    const int blocks = NDATA / (4 * 8 * NB);   // 2048, exact

    deepset_kernel<<<blocks, 256, 0, stream>>>(
        x, phi_w1, phi_b1, phi_w2, phi_b2,
        rho_w1, rho_b1, rho_w2, rho_b2, out);
}